// Round 1
// baseline (971.733 us; speedup 1.0000x reference)
//
#include <hip/hip_runtime.h>
#include <math.h>

#define BB   32
#define HQn  32
#define HKVn 8
#define Dn   128
#define Sn   4096
#define Gn   4        // HQ / HKV
#define NWAVES 16
#define TPH  (Sn / (NWAVES * 2))   // tokens per half-wave = 128
#define SCALING 0.08838834764831845f

// ---------------------------------------------------------------------------
// Scatter the current step's K/V into the pools at out_cache_loc.
// B*HKV*D = 32768 elements per tensor; t = b*1024 + h*128 + d.
// ---------------------------------------------------------------------------
__global__ void scatter_kv(const float* __restrict__ k, const float* __restrict__ v,
                           const int* __restrict__ loc,
                           float* __restrict__ kp, float* __restrict__ vp) {
    int t  = blockIdx.x * blockDim.x + threadIdx.x;   // [0, 32768)
    int b  = t >> 10;                                 // HKV*D = 1024
    int hd = t & 1023;
    int p  = loc[b];
    size_t dst = (size_t)p * (HKVn * Dn) + hd;
    kp[dst] = k[t];
    vp[dst] = v[t];
}

// ---------------------------------------------------------------------------
// One block per (b, hkv). 1024 threads = 16 waves, 4 waves/SIMD.
// Each half-wave (32 lanes) processes one token at a time: lane c holds
// elements [4c, 4c+4) of the K/V row (float4). Online softmax per head.
// ---------------------------------------------------------------------------
__launch_bounds__(1024, 1)
__global__ void attn_decode(const float* __restrict__ q,
                            const float* __restrict__ k_pool,
                            const float* __restrict__ v_pool,
                            const int*   __restrict__ kv_indices,
                            float* __restrict__ out) {
    const int bh   = blockIdx.x;       // b*HKV + hkv
    const int b    = bh >> 3;
    const int hkv  = bh & 7;
    const int tid  = threadIdx.x;
    const int wave = tid >> 6;
    const int lane = tid & 63;
    const int half = lane >> 5;
    const int c    = lane & 31;
    const int part = wave * 2 + half;  // half-wave id, 0..31

    __shared__ float s_out[NWAVES][Gn][Dn];  // 32 KB
    __shared__ float s_m[NWAVES][Gn];
    __shared__ float s_l[NWAVES][Gn];

    // q fragment per head, pre-scaled by SCALING
    float4 qf[Gn];
#pragma unroll
    for (int g = 0; g < Gn; g++) {
        const float4* q4 = (const float4*)(q + ((size_t)b * HQn + hkv * Gn + g) * Dn);
        float4 t = q4[c];
        qf[g] = make_float4(t.x * SCALING, t.y * SCALING, t.z * SCALING, t.w * SCALING);
    }

    const int*    idxrow = kv_indices + (size_t)b * Sn;
    const float4* kp4 = (const float4*)k_pool;
    const float4* vp4 = (const float4*)v_pool;
    const int rowstride = HKVn * Dn / 4;   // float4 per pool row = 256
    const int hoff      = hkv * (Dn / 4);  // + c gives this lane's slot

    float  m[Gn], l[Gn];
    float4 acc[Gn];
#pragma unroll
    for (int g = 0; g < Gn; g++) {
        m[g] = -INFINITY; l[g] = 0.f;
        acc[g] = make_float4(0.f, 0.f, 0.f, 0.f);
    }

    // token for iteration i: s = i*32 + part  (block streams 32 rows/step)
    int    idx0 = idxrow[part];
    float4 kf = kp4[(size_t)idx0 * rowstride + hoff + c];
    float4 vf = vp4[(size_t)idx0 * rowstride + hoff + c];

    for (int i = 0; i < TPH; i++) {
        // prefetch next token (wraps to token `part` on the last iter; harmless)
        int sn = i * 32 + part + 32;
        if (sn >= Sn) sn -= Sn;
        int idxn = idxrow[sn];
        float4 kn = kp4[(size_t)idxn * rowstride + hoff + c];
        float4 vn = vp4[(size_t)idxn * rowstride + hoff + c];

#pragma unroll
        for (int g = 0; g < Gn; g++) {
            float dot = qf[g].x * kf.x + qf[g].y * kf.y + qf[g].z * kf.z + qf[g].w * kf.w;
            dot += __shfl_xor(dot, 1, 64);
            dot += __shfl_xor(dot, 2, 64);
            dot += __shfl_xor(dot, 4, 64);
            dot += __shfl_xor(dot, 8, 64);
            dot += __shfl_xor(dot, 16, 64);
            // branchless online softmax
            float mn    = fmaxf(m[g], dot);
            float scale = __expf(m[g] - mn);
            float w     = __expf(dot - mn);
            m[g] = mn;
            l[g] = l[g] * scale + w;
            acc[g].x = acc[g].x * scale + w * vf.x;
            acc[g].y = acc[g].y * scale + w * vf.y;
            acc[g].z = acc[g].z * scale + w * vf.z;
            acc[g].w = acc[g].w * scale + w * vf.w;
        }
        kf = kn; vf = vn;
    }

    // merge the two half-waves inside each wave (shuffle across lane^32)
#pragma unroll
    for (int g = 0; g < Gn; g++) {
        float mo = __shfl_xor(m[g], 32, 64);
        float lo = __shfl_xor(l[g], 32, 64);
        float4 ao;
        ao.x = __shfl_xor(acc[g].x, 32, 64);
        ao.y = __shfl_xor(acc[g].y, 32, 64);
        ao.z = __shfl_xor(acc[g].z, 32, 64);
        ao.w = __shfl_xor(acc[g].w, 32, 64);
        float M  = fmaxf(m[g], mo);
        float w1 = __expf(m[g] - M);
        float w2 = __expf(mo   - M);
        m[g] = M;
        l[g] = l[g] * w1 + lo * w2;
        acc[g].x = acc[g].x * w1 + ao.x * w2;
        acc[g].y = acc[g].y * w1 + ao.y * w2;
        acc[g].z = acc[g].z * w1 + ao.z * w2;
        acc[g].w = acc[g].w * w1 + ao.w * w2;
    }

    if (half == 0) {
#pragma unroll
        for (int g = 0; g < Gn; g++) {
            ((float4*)&s_out[wave][g][0])[c] = acc[g];
            if (c == 0) { s_m[wave][g] = m[g]; s_l[wave][g] = l[g]; }
        }
    }
    __syncthreads();

    // final merge across the 16 wave-partials; 512 threads write G*D outputs
    if (tid < Gn * Dn) {
        int g = tid >> 7;
        int d = tid & 127;
        float M = -INFINITY;
#pragma unroll
        for (int p = 0; p < NWAVES; p++) M = fmaxf(M, s_m[p][g]);
        float L = 0.f, O = 0.f;
#pragma unroll
        for (int p = 0; p < NWAVES; p++) {
            float w = __expf(s_m[p][g] - M);
            L += w * s_l[p][g];
            O += w * s_out[p][g][d];
        }
        out[((size_t)b * HQn + hkv * Gn + g) * Dn + d] = O / L;
    }
}

extern "C" void kernel_launch(void* const* d_in, const int* in_sizes, int n_in,
                              void* d_out, int out_size, void* d_ws, size_t ws_size,
                              hipStream_t stream) {
    const float* q       = (const float*)d_in[0];
    const float* k       = (const float*)d_in[1];
    const float* v       = (const float*)d_in[2];
    float* k_pool        = (float*)d_in[3];   // mutated; harness restores pre-launch
    float* v_pool        = (float*)d_in[4];
    const int* kv_indices    = (const int*)d_in[5];
    const int* out_cache_loc = (const int*)d_in[6];
    float* out = (float*)d_out;

    scatter_kv<<<(BB * HKVn * Dn) / 256, 256, 0, stream>>>(k, v, out_cache_loc, k_pool, v_pool);
    attn_decode<<<BB * HKVn, 1024, 0, stream>>>(q, k_pool, v_pool, kv_indices, out);
}

// Round 2
// 930.552 us; speedup vs baseline: 1.0443x; 1.0443x over previous
//
#include <hip/hip_runtime.h>
#include <math.h>

#define BB   32
#define HQn  32
#define HKVn 8
#define Dn   128
#define Sn   4096
#define Gn   4        // HQ / HKV
#define NWAVES 16
#define NHW   (NWAVES * 2)          // 32 half-waves per block
#define TOKITER (Sn / (NHW * 2))    // 64 iterations, 2 tokens per half-wave each
#define SCALING 0.08838834764831845f

typedef float f32x4 __attribute__((ext_vector_type(4)));

// ---------------------------------------------------------------------------
// Scatter the current step's K/V into the pools at out_cache_loc.
// ---------------------------------------------------------------------------
__global__ void scatter_kv(const float* __restrict__ k, const float* __restrict__ v,
                           const int* __restrict__ loc,
                           float* __restrict__ kp, float* __restrict__ vp) {
    int t  = blockIdx.x * blockDim.x + threadIdx.x;   // [0, 32768)
    int b  = t >> 10;                                 // HKV*D = 1024
    int hd = t & 1023;
    int p  = loc[b];
    size_t dst = (size_t)p * (HKVn * Dn) + hd;
    kp[dst] = k[t];
    vp[dst] = v[t];
}

// ---------------------------------------------------------------------------
// One block per (b, hkv). 1024 threads = 16 waves. Each half-wave (32 lanes)
// processes 2 tokens per iteration; lane c holds elements [4c,4c+4) of each
// K/V row. Indices preloaded into registers (no per-iter index load chain).
// ---------------------------------------------------------------------------
__launch_bounds__(1024, 1)
__global__ void attn_decode(const float* __restrict__ q,
                            const float* __restrict__ k_pool,
                            const float* __restrict__ v_pool,
                            const int*   __restrict__ kv_indices,
                            float* __restrict__ out) {
    const int bh   = blockIdx.x;       // b*HKV + hkv
    const int b    = bh >> 3;
    const int hkv  = bh & 7;
    const int tid  = threadIdx.x;
    const int wave = tid >> 6;
    const int lane = tid & 63;
    const int half = lane >> 5;
    const int c    = lane & 31;
    const int part = wave * 2 + half;  // half-wave id, 0..31

    __shared__ float s_out[NWAVES][Gn][Dn];  // 32 KB
    __shared__ float s_m[NWAVES][Gn];
    __shared__ float s_l[NWAVES][Gn];

    // q fragment per head, pre-scaled by SCALING
    f32x4 qf[Gn];
#pragma unroll
    for (int g = 0; g < Gn; g++) {
        const f32x4* q4 = (const f32x4*)(q + ((size_t)b * HQn + hkv * Gn + g) * Dn);
        qf[g] = q4[c] * SCALING;
    }

    const int* idxrow = kv_indices + (size_t)b * Sn;
    // Preload this half-wave's 128 token indices into 4 regs/lane.
    // reg r: j = r>>1 (token slot), i = (r&1)*32 + c (iteration) ->
    // s = i*64 + part*2 + j
    int ireg[4];
#pragma unroll
    for (int r = 0; r < 4; r++) {
        int i = (r & 1) * 32 + c;
        int j = r >> 1;
        ireg[r] = idxrow[i * 64 + part * 2 + j];
    }

    const f32x4* kp4 = (const f32x4*)k_pool;
    const f32x4* vp4 = (const f32x4*)v_pool;
    const int rowstride = HKVn * Dn / 4;       // 256 f32x4 per pool row
    const int hoff      = hkv * (Dn / 4) + c;  // this lane's slot in a row

    float m[Gn], l[Gn];
    f32x4 acc[Gn];
#pragma unroll
    for (int g = 0; g < Gn; g++) {
        m[g] = -INFINITY; l[g] = 0.f;
        acc[g] = (f32x4)(0.f);
    }

    // initial fetch (iteration 0)
    int idx0 = __shfl(ireg[0], 0, 32);
    int idx1 = __shfl(ireg[2], 0, 32);
    f32x4 kf0 = __builtin_nontemporal_load(kp4 + (size_t)idx0 * rowstride + hoff);
    f32x4 vf0 = __builtin_nontemporal_load(vp4 + (size_t)idx0 * rowstride + hoff);
    f32x4 kf1 = __builtin_nontemporal_load(kp4 + (size_t)idx1 * rowstride + hoff);
    f32x4 vf1 = __builtin_nontemporal_load(vp4 + (size_t)idx1 * rowstride + hoff);

    for (int i = 0; i < TOKITER; i++) {
        // prefetch next iteration (last iter re-reads current rows: L1-hot)
        int inext = (i < TOKITER - 1) ? i + 1 : i;
        int rb  = inext >> 5;
        int src = inext & 31;
        int nidx0 = __shfl(ireg[rb],     src, 32);
        int nidx1 = __shfl(ireg[2 + rb], src, 32);
        f32x4 kn0 = __builtin_nontemporal_load(kp4 + (size_t)nidx0 * rowstride + hoff);
        f32x4 vn0 = __builtin_nontemporal_load(vp4 + (size_t)nidx0 * rowstride + hoff);
        f32x4 kn1 = __builtin_nontemporal_load(kp4 + (size_t)nidx1 * rowstride + hoff);
        f32x4 vn1 = __builtin_nontemporal_load(vp4 + (size_t)nidx1 * rowstride + hoff);

#pragma unroll
        for (int g = 0; g < Gn; g++) {
            float d0 = qf[g].x * kf0.x + qf[g].y * kf0.y + qf[g].z * kf0.z + qf[g].w * kf0.w;
            float d1 = qf[g].x * kf1.x + qf[g].y * kf1.y + qf[g].z * kf1.z + qf[g].w * kf1.w;
            d0 += __shfl_xor(d0, 1, 64);  d1 += __shfl_xor(d1, 1, 64);
            d0 += __shfl_xor(d0, 2, 64);  d1 += __shfl_xor(d1, 2, 64);
            d0 += __shfl_xor(d0, 4, 64);  d1 += __shfl_xor(d1, 4, 64);
            d0 += __shfl_xor(d0, 8, 64);  d1 += __shfl_xor(d1, 8, 64);
            d0 += __shfl_xor(d0, 16, 64); d1 += __shfl_xor(d1, 16, 64);
            // branchless online softmax, one rescale per 2 tokens
            float mn = fmaxf(m[g], fmaxf(d0, d1));
            float sc = __expf(m[g] - mn);
            float w0 = __expf(d0 - mn);
            float w1 = __expf(d1 - mn);
            m[g] = mn;
            l[g] = l[g] * sc + w0 + w1;
            acc[g] = acc[g] * sc + vf0 * w0 + vf1 * w1;
        }
        kf0 = kn0; vf0 = vn0; kf1 = kn1; vf1 = vn1;
    }

    // merge the two half-waves inside each wave (shuffle across lane^32)
#pragma unroll
    for (int g = 0; g < Gn; g++) {
        float mo = __shfl_xor(m[g], 32, 64);
        float lo = __shfl_xor(l[g], 32, 64);
        f32x4 ao;
        ao.x = __shfl_xor(acc[g].x, 32, 64);
        ao.y = __shfl_xor(acc[g].y, 32, 64);
        ao.z = __shfl_xor(acc[g].z, 32, 64);
        ao.w = __shfl_xor(acc[g].w, 32, 64);
        float M  = fmaxf(m[g], mo);
        float w1 = __expf(m[g] - M);
        float w2 = __expf(mo   - M);
        m[g] = M;
        l[g] = l[g] * w1 + lo * w2;
        acc[g] = acc[g] * w1 + ao * w2;
    }

    if (half == 0) {
#pragma unroll
        for (int g = 0; g < Gn; g++) {
            ((f32x4*)&s_out[wave][g][0])[c] = acc[g];
            if (c == 0) { s_m[wave][g] = m[g]; s_l[wave][g] = l[g]; }
        }
    }
    __syncthreads();

    // final merge across the 16 wave-partials; 512 threads write G*D outputs
    if (tid < Gn * Dn) {
        int g = tid >> 7;
        int d = tid & 127;
        float M = -INFINITY;
#pragma unroll
        for (int p = 0; p < NWAVES; p++) M = fmaxf(M, s_m[p][g]);
        float L = 0.f, O = 0.f;
#pragma unroll
        for (int p = 0; p < NWAVES; p++) {
            float w = __expf(s_m[p][g] - M);
            L += w * s_l[p][g];
            O += w * s_out[p][g][d];
        }
        out[((size_t)b * HQn + hkv * Gn + g) * Dn + d] = O / L;
    }
}

extern "C" void kernel_launch(void* const* d_in, const int* in_sizes, int n_in,
                              void* d_out, int out_size, void* d_ws, size_t ws_size,
                              hipStream_t stream) {
    const float* q       = (const float*)d_in[0];
    const float* k       = (const float*)d_in[1];
    const float* v       = (const float*)d_in[2];
    float* k_pool        = (float*)d_in[3];   // mutated; harness restores pre-launch
    float* v_pool        = (float*)d_in[4];
    const int* kv_indices    = (const int*)d_in[5];
    const int* out_cache_loc = (const int*)d_in[6];
    float* out = (float*)d_out;

    scatter_kv<<<(BB * HKVn * Dn) / 256, 256, 0, stream>>>(k, v, out_cache_loc, k_pool, v_pool);
    attn_decode<<<BB * HKVn, 1024, 0, stream>>>(q, k_pool, v_pool, kv_indices, out);
}